// Round 3
// baseline (181.436 us; speedup 1.0000x reference)
//
#include <hip/hip_runtime.h>
#include <hip/hip_bf16.h>
#include <stdint.h>

// exp(s/sqrt(128)) = exp2(s * log2(e)/sqrt(128)); folded into Q at k_qk epilogue
#define SCALE_LOG2E 0.12751743f

typedef __bf16 bf16x8 __attribute__((ext_vector_type(8)));
typedef float floatx4 __attribute__((ext_vector_type(4)));
typedef uint32_t u32x4v __attribute__((ext_vector_type(4)));

__device__ __forceinline__ bf16x8 load_bf8(const void* p) {
    u32x4v v = *(const u32x4v*)p;
    return __builtin_bit_cast(bf16x8, v);
}

__device__ __forceinline__ bf16x8 cvt8(float4 u, float4 v) {
    union { bf16x8 v8; __hip_bfloat16 h[8]; } r;
    r.h[0] = __float2bfloat16(u.x); r.h[1] = __float2bfloat16(u.y);
    r.h[2] = __float2bfloat16(u.z); r.h[3] = __float2bfloat16(u.w);
    r.h[4] = __float2bfloat16(v.x); r.h[5] = __float2bfloat16(v.y);
    r.h[6] = __float2bfloat16(v.z); r.h[7] = __float2bfloat16(v.w);
    return r.v8;
}

// ---------------------------------------------------------------------------
// Kernel A: convert w_q, w_k to bf16; compute c[768] = w_o @ w_v
// ---------------------------------------------------------------------------
__global__ void k_prep(const float* __restrict__ w_q, const float* __restrict__ w_k,
                       const float* __restrict__ w_v, const float* __restrict__ w_o,
                       __hip_bfloat16* __restrict__ wq_bf,
                       __hip_bfloat16* __restrict__ wk_bf,
                       float* __restrict__ c_out) {
    int b = blockIdx.x;
    int t = threadIdx.x;
    if (b < 96) {
        #pragma unroll
        for (int p = 0; p < 8; ++p) {
            int i = b * 2048 + p * 256 + t;
            if (i < 98304) wq_bf[i] = __float2bfloat16(w_q[i]);
            else           wk_bf[i - 98304] = __float2bfloat16(w_k[i - 98304]);
        }
    } else {
        int j = (b - 96) * 256 + t;
        if (j < 768) {
            float acc = 0.f;
            #pragma unroll 8
            for (int k = 0; k < 64; ++k) acc += w_o[k] * w_v[k * 768 + j];
            c_out[j] = acc;
        }
    }
}

// ---------------------------------------------------------------------------
// Kernel B: Q = x1 @ w_q^T * SCALE (bid 0..255), K = x2 @ w_k^T (bid 256..511),
// + vs for K blocks. Block = 128 rows x 32 cols; each wave a DISJOINT 32 rows
// (A read exactly once). LDS-free. Explicit distance-2 register pipeline so
// ~2 load-groups (12 KB/wave) stay in flight -> HBM-BW-bound, not latency.
// launch_bounds(256,2): VGPR cap 256 so the pipeline stages fit.
// ---------------------------------------------------------------------------
__global__ __launch_bounds__(256, 2) void k_qk(
        const float* __restrict__ x1, const float* __restrict__ x2,
        const __hip_bfloat16* __restrict__ wq_bf,
        const __hip_bfloat16* __restrict__ wk_bf,
        const float* __restrict__ c_in,
        __hip_bfloat16* __restrict__ Qb, __hip_bfloat16* __restrict__ Kb,
        float* __restrict__ vs_g) {
    int bid = blockIdx.x;
    bool isK = bid >= 256;
    int b = bid & 255;
    int t = threadIdx.x;
    int wave = t >> 6, lane = t & 63;
    int m = lane & 15, quad = lane >> 4;
    int row0 = (b >> 2) * 128 + wave * 32;   // this wave's 32 rows
    int col0 = (b & 3) * 32;                 // block's 32 cols

    const float* x = isK ? x2 : x1;
    const __hip_bfloat16* w = isK ? wk_bf : wq_bf;
    __hip_bfloat16* outp = isK ? Kb : Qb;

    const float* a0p = x + (size_t)(row0 + m) * 768 + quad * 8;
    const float* a1p = a0p + 16 * 768;
    const __hip_bfloat16* b0p = w + (size_t)(col0 + m) * 768 + quad * 8;
    const __hip_bfloat16* b1p = b0p + 16 * 768;

    floatx4 acc[2][2];
    #pragma unroll
    for (int i = 0; i < 2; ++i)
        #pragma unroll
        for (int j = 0; j < 2; ++j) acc[i][j] = {0.f, 0.f, 0.f, 0.f};

    struct Stage { float4 u0, v0, u1, v1; bf16x8 b0, b1; };
    auto ld = [&](int kc) {
        Stage s;
        s.u0 = *(const float4*)(a0p + kc);
        s.v0 = *(const float4*)(a0p + kc + 4);
        s.u1 = *(const float4*)(a1p + kc);
        s.v1 = *(const float4*)(a1p + kc + 4);
        s.b0 = load_bf8(b0p + kc);
        s.b1 = load_bf8(b1p + kc);
        return s;
    };

    Stage s0 = ld(0), s1 = ld(32);
    #pragma unroll
    for (int k = 0; k < 24; ++k) {
        Stage s2 = s1;
        if (k + 2 < 24) s2 = ld((k + 2) * 32);
        bf16x8 A0 = cvt8(s0.u0, s0.v0);
        bf16x8 A1 = cvt8(s0.u1, s0.v1);
        acc[0][0] = __builtin_amdgcn_mfma_f32_16x16x32_bf16(A0, s0.b0, acc[0][0], 0, 0, 0);
        acc[0][1] = __builtin_amdgcn_mfma_f32_16x16x32_bf16(A0, s0.b1, acc[0][1], 0, 0, 0);
        acc[1][0] = __builtin_amdgcn_mfma_f32_16x16x32_bf16(A1, s0.b0, acc[1][0], 0, 0, 0);
        acc[1][1] = __builtin_amdgcn_mfma_f32_16x16x32_bf16(A1, s0.b1, acc[1][1], 0, 0, 0);
        s0 = s1; s1 = s2;
    }

    // vs[row] = x2[row] . c : only K blocks with col-group 0; 2 threads/row
    if (isK && (b & 3) == 0) {
        int rb0 = (b >> 2) * 128;
        int r = t >> 1, h = t & 1;
        const float* xr = x + (size_t)(rb0 + r) * 768 + h * 384;
        const float* cr = c_in + h * 384;
        float vacc = 0.f;
        #pragma unroll 8
        for (int j = 0; j < 384; j += 4) {
            float4 v = *(const float4*)(xr + j);
            vacc += v.x * cr[j] + v.y * cr[j + 1] + v.z * cr[j + 2] + v.w * cr[j + 3];
        }
        vacc += __shfl_xor(vacc, 1, 64);
        if (h == 0) vs_g[rb0 + r] = vacc;
    }

    // write C (bf16), Q side pre-scaled by SCALE_LOG2E.
    // C layout: col=lane&15, row=quad*4+reg
    float cscale = isK ? 1.0f : SCALE_LOG2E;
    #pragma unroll
    for (int i = 0; i < 2; ++i)
        #pragma unroll
        for (int j = 0; j < 2; ++j)
            #pragma unroll
            for (int r = 0; r < 4; ++r) {
                int row = row0 + i * 16 + quad * 4 + r;
                int col = col0 + j * 16 + m;
                outp[(size_t)row * 128 + col] = __float2bfloat16(acc[i][j][r] * cscale);
            }
}

// ---------------------------------------------------------------------------
// Kernel C: flash-style attention row-sums. Q-fragments hoisted into registers
// (loop-invariant, loaded once from global); only K tile round-trips LDS.
// grid 512 = 64 q-blocks x 8 t-chunks. p = exp2(S) since Q was pre-scaled.
// ---------------------------------------------------------------------------
__global__ __launch_bounds__(256, 2) void k_attn(
        const __hip_bfloat16* __restrict__ Qb, const __hip_bfloat16* __restrict__ Kb,
        const float* __restrict__ vs_g,
        float* __restrict__ num_g, float* __restrict__ den_g) {
    constexpr int LDK = 136;  // 128 + 8 pad
    __shared__ alignas(16) __hip_bfloat16 sK[128 * LDK];
    __shared__ float sVS[1024];

    int bid = blockIdx.x;
    int qb = bid >> 3, tc = bid & 7;
    int q0 = qb * 128, t0 = tc * 1024;

    int t = threadIdx.x;
    int wave = t >> 6, lane = t & 63;
    int wr = wave >> 1, wc = wave & 1;
    int m = lane & 15, quad = lane >> 4;

    // Q fragments, loop-invariant: qf[kk][i], A-layout A[m][k=quad*8+j]
    bf16x8 qf[4][4];
    #pragma unroll
    for (int i = 0; i < 4; ++i)
        #pragma unroll
        for (int kk = 0; kk < 4; ++kk)
            qf[kk][i] = load_bf8(Qb + (size_t)(q0 + wr * 64 + i * 16 + m) * 128 + kk * 32 + quad * 8);

    #pragma unroll
    for (int p = 0; p < 4; ++p) sVS[p * 256 + t] = vs_g[t0 + p * 256 + t];

    // preload K tile 0 into registers
    u32x4v kreg[8];
    #pragma unroll
    for (int p = 0; p < 8; ++p) {
        int f = p * 256 + t;
        int r = f >> 4, c = (f & 15) * 8;
        kreg[p] = *(const u32x4v*)(Kb + (size_t)(t0 + r) * 128 + c);
    }

    float num_acc[4][4], den_acc[4][4];
    #pragma unroll
    for (int i = 0; i < 4; ++i)
        #pragma unroll
        for (int r = 0; r < 4; ++r) { num_acc[i][r] = 0.f; den_acc[i][r] = 0.f; }

    for (int it = 0; it < 8; ++it) {
        __syncthreads();  // previous iter's sK reads done (no-op cost at it=0)
        #pragma unroll
        for (int p = 0; p < 8; ++p) {
            int f = p * 256 + t;
            int r = f >> 4, c = (f & 15) * 8;
            *(u32x4v*)(&sK[r * LDK + c]) = kreg[p];
        }
        __syncthreads();
        if (it < 7) {
            #pragma unroll
            for (int p = 0; p < 8; ++p) {
                int f = p * 256 + t;
                int r = f >> 4, c = (f & 15) * 8;
                kreg[p] = *(const u32x4v*)(Kb + (size_t)(t0 + (it + 1) * 128 + r) * 128 + c);
            }
        }

        floatx4 acc[4][4];
        #pragma unroll
        for (int i = 0; i < 4; ++i)
            #pragma unroll
            for (int j = 0; j < 4; ++j) acc[i][j] = {0.f, 0.f, 0.f, 0.f};

        #pragma unroll
        for (int kk = 0; kk < 4; ++kk) {
            bf16x8 bfr[4];
            #pragma unroll
            for (int j = 0; j < 4; ++j)
                bfr[j] = load_bf8(&sK[(wc * 64 + j * 16 + m) * LDK + kk * 32 + quad * 8]);
            #pragma unroll
            for (int i = 0; i < 4; ++i)
                #pragma unroll
                for (int j = 0; j < 4; ++j)
                    acc[i][j] = __builtin_amdgcn_mfma_f32_16x16x32_bf16(qf[kk][i], bfr[j], acc[i][j], 0, 0, 0);
        }

        #pragma unroll
        for (int j = 0; j < 4; ++j) {
            float vsv = sVS[it * 128 + wc * 64 + j * 16 + m];
            #pragma unroll
            for (int i = 0; i < 4; ++i)
                #pragma unroll
                for (int r = 0; r < 4; ++r) {
                    float p = __builtin_amdgcn_exp2f(acc[i][j][r]);
                    den_acc[i][r] += p;
                    num_acc[i][r] += p * vsv;
                }
        }
    }

    #pragma unroll
    for (int i = 0; i < 4; ++i)
        #pragma unroll
        for (int r = 0; r < 4; ++r) {
            float n = num_acc[i][r], d = den_acc[i][r];
            #pragma unroll
            for (int mask = 1; mask <= 8; mask <<= 1) {
                n += __shfl_xor(n, mask, 64);
                d += __shfl_xor(d, mask, 64);
            }
            if ((lane & 15) == 0) {
                int row = q0 + wr * 64 + i * 16 + quad * 4 + r;
                atomicAdd(&num_g[row], n);
                atomicAdd(&den_g[row], d);
            }
        }
}

// ---------------------------------------------------------------------------
// Kernel D: gated = x1 * (1 - num/den). float4 grid-mapped, memory-bound.
// ---------------------------------------------------------------------------
__global__ void k_final(const float* __restrict__ x1,
                        const float* __restrict__ num_g,
                        const float* __restrict__ den_g,
                        float* __restrict__ outp) {
    int idx = blockIdx.x * 256 + threadIdx.x;  // float4 index, 192 per row
    int s = idx / 192;
    float4 v = *(const float4*)(x1 + (size_t)idx * 4);
    float g = 1.0f - num_g[s] / den_g[s];
    float4 rv;
    rv.x = v.x * g; rv.y = v.y * g; rv.z = v.z * g; rv.w = v.w * g;
    *(float4*)(outp + (size_t)idx * 4) = rv;
}

// ---------------------------------------------------------------------------
extern "C" void kernel_launch(void* const* d_in, const int* in_sizes, int n_in,
                              void* d_out, int out_size, void* d_ws, size_t ws_size,
                              hipStream_t stream) {
    const float* x1  = (const float*)d_in[0];
    const float* x2  = (const float*)d_in[1];
    const float* w_q = (const float*)d_in[2];
    const float* w_k = (const float*)d_in[3];
    const float* w_v = (const float*)d_in[4];
    const float* w_o = (const float*)d_in[5];
    float* outp = (float*)d_out;

    char* ws = (char*)d_ws;
    __hip_bfloat16* wq_bf = (__hip_bfloat16*)(ws + 0);        // 196608 B
    __hip_bfloat16* wk_bf = (__hip_bfloat16*)(ws + 196608);   // 196608 B
    float* c_buf          = (float*)(ws + 393216);            // 3072 B
    __hip_bfloat16* Qb    = (__hip_bfloat16*)(ws + 396288);   // 2 MB
    __hip_bfloat16* Kb    = (__hip_bfloat16*)(ws + 2493440);  // 2 MB
    float* vs_g           = (float*)(ws + 4590592);           // 32 KB
    float* num_g          = (float*)(ws + 4623360);           // 32 KB
    float* den_g          = (float*)(ws + 4656128);           // 32 KB

    hipMemsetAsync(num_g, 0, 8192 * sizeof(float), stream);
    hipMemsetAsync(den_g, 0, 8192 * sizeof(float), stream);

    k_prep<<<100, 256, 0, stream>>>(w_q, w_k, w_v, w_o, wq_bf, wk_bf, c_buf);
    k_qk<<<512, 256, 0, stream>>>(x1, x2, wq_bf, wk_bf, c_buf, Qb, Kb, vs_g);
    k_attn<<<512, 256, 0, stream>>>(Qb, Kb, vs_g, num_g, den_g);
    k_final<<<6144, 256, 0, stream>>>(x1, num_g, den_g, outp);
}

// Round 4
// 178.074 us; speedup vs baseline: 1.0189x; 1.0189x over previous
//
#include <hip/hip_runtime.h>
#include <hip/hip_bf16.h>
#include <stdint.h>

// exp(s/sqrt(128)) = exp2(s * log2(e)/sqrt(128)); folded into Q at k_qk epilogue
#define SCALE_LOG2E 0.12751743f

typedef __bf16 bf16x8 __attribute__((ext_vector_type(8)));
typedef float floatx4 __attribute__((ext_vector_type(4)));
typedef uint32_t u32x4v __attribute__((ext_vector_type(4)));

__device__ __forceinline__ bf16x8 load_bf8(const void* p) {
    u32x4v v = *(const u32x4v*)p;
    return __builtin_bit_cast(bf16x8, v);
}

__device__ __forceinline__ bf16x8 cvt8(float4 u, float4 v) {
    union { bf16x8 v8; __hip_bfloat16 h[8]; } r;
    r.h[0] = __float2bfloat16(u.x); r.h[1] = __float2bfloat16(u.y);
    r.h[2] = __float2bfloat16(u.z); r.h[3] = __float2bfloat16(u.w);
    r.h[4] = __float2bfloat16(v.x); r.h[5] = __float2bfloat16(v.y);
    r.h[6] = __float2bfloat16(v.z); r.h[7] = __float2bfloat16(v.w);
    return r.v8;
}

// ---------------------------------------------------------------------------
// Kernel A: cvt w_q,w_k -> bf16 (b<96); c[768] = w_o @ w_v (b 96..98);
// zero num/den (b 99..131; num_g/den_g are CONTIGUOUS 16384 floats in ws).
// ---------------------------------------------------------------------------
__global__ void k_prep(const float* __restrict__ w_q, const float* __restrict__ w_k,
                       const float* __restrict__ w_v, const float* __restrict__ w_o,
                       __hip_bfloat16* __restrict__ wq_bf,
                       __hip_bfloat16* __restrict__ wk_bf,
                       float* __restrict__ c_out,
                       float* __restrict__ numden) {
    int b = blockIdx.x;
    int t = threadIdx.x;
    if (b < 96) {
        #pragma unroll
        for (int p = 0; p < 8; ++p) {
            int i = b * 2048 + p * 256 + t;
            if (i < 98304) wq_bf[i] = __float2bfloat16(w_q[i]);
            else           wk_bf[i - 98304] = __float2bfloat16(w_k[i - 98304]);
        }
    } else if (b < 99) {
        int j = (b - 96) * 256 + t;
        float acc = 0.f;
        #pragma unroll 8
        for (int k = 0; k < 64; ++k) acc += w_o[k] * w_v[k * 768 + j];
        c_out[j] = acc;
    } else {
        int z = (b - 99) * 512 + t * 2;
        if (z < 16384) { numden[z] = 0.f; numden[z + 1] = 0.f; }
    }
}

// ---------------------------------------------------------------------------
// Kernel B: Q = x1 @ w_q^T * SCALE (bid 0..511), K = x2 @ w_k^T (512..1023),
// vs = x2 . c (bid 1024..1279).
// GEMM block = 16 rows x 128 cols, 4 waves; wave = 16x32, acc = 8 VGPRs.
// Each 16-row stripe read exactly ONCE (waves share rows via L1). K-chunk 64,
// distance-1 register pipeline, 8 independent loads per iter.
// launch_bounds(256,4): 4+ waves/SIMD so waits overlap across waves.
// ---------------------------------------------------------------------------
__global__ __launch_bounds__(256, 4) void k_qk(
        const float* __restrict__ x1, const float* __restrict__ x2,
        const __hip_bfloat16* __restrict__ wq_bf,
        const __hip_bfloat16* __restrict__ wk_bf,
        const float* __restrict__ c_in,
        __hip_bfloat16* __restrict__ Qb, __hip_bfloat16* __restrict__ Kb,
        float* __restrict__ vs_g) {
    int bid = blockIdx.x;
    int t = threadIdx.x;

    if (bid >= 1024) {
        // ---- vs blocks: 256 blocks x 32 rows, 8 threads per row ----
        int vb = bid - 1024;
        int r = vb * 32 + (t >> 3), h = t & 7;
        const float* xr = x2 + (size_t)r * 768 + h * 96;
        const float* cr = c_in + h * 96;
        float vacc = 0.f;
        #pragma unroll 6
        for (int j = 0; j < 96; j += 4) {
            float4 v = *(const float4*)(xr + j);
            vacc += v.x * cr[j] + v.y * cr[j + 1] + v.z * cr[j + 2] + v.w * cr[j + 3];
        }
        vacc += __shfl_xor(vacc, 1, 64);
        vacc += __shfl_xor(vacc, 2, 64);
        vacc += __shfl_xor(vacc, 4, 64);
        if (h == 0) vs_g[r] = vacc;
        return;
    }

    bool isK = bid >= 512;
    int row0 = (bid & 511) * 16;
    const float* x = isK ? x2 : x1;
    const __hip_bfloat16* w = isK ? wk_bf : wq_bf;
    __hip_bfloat16* outp = isK ? Kb : Qb;

    int wave = t >> 6, lane = t & 63;
    int m = lane & 15, quad = lane >> 4;
    int col0 = wave * 32;

    // lane-invariant base pointers
    const float* ap = x + (size_t)(row0 + m) * 768 + quad * 8;           // A row m
    const __hip_bfloat16* bp0 = w + (size_t)(col0 + m) * 768 + quad * 8; // B col grp j=0
    const __hip_bfloat16* bp1 = bp0 + (size_t)16 * 768;                  // j=1

    floatx4 acc0 = {0.f, 0.f, 0.f, 0.f}, acc1 = {0.f, 0.f, 0.f, 0.f};

    struct Stage { float4 a0, a1, a2, a3; bf16x8 b0, b1, b2, b3; };
    auto ld = [&](int kc) {
        Stage s;
        s.a0 = *(const float4*)(ap + kc);          // kk=0, low half
        s.a1 = *(const float4*)(ap + kc + 4);      // kk=0, high half
        s.a2 = *(const float4*)(ap + kc + 32);     // kk=1, low half
        s.a3 = *(const float4*)(ap + kc + 36);     // kk=1, high half
        s.b0 = load_bf8(bp0 + kc);
        s.b1 = load_bf8(bp1 + kc);
        s.b2 = load_bf8(bp0 + kc + 32);
        s.b3 = load_bf8(bp1 + kc + 32);
        return s;
    };

    Stage cur = ld(0);
    #pragma unroll
    for (int it = 0; it < 12; ++it) {
        Stage nxt = cur;
        if (it < 11) nxt = ld((it + 1) * 64);
        bf16x8 afr0 = cvt8(cur.a0, cur.a1);
        bf16x8 afr1 = cvt8(cur.a2, cur.a3);
        acc0 = __builtin_amdgcn_mfma_f32_16x16x32_bf16(afr0, cur.b0, acc0, 0, 0, 0);
        acc1 = __builtin_amdgcn_mfma_f32_16x16x32_bf16(afr0, cur.b1, acc1, 0, 0, 0);
        acc0 = __builtin_amdgcn_mfma_f32_16x16x32_bf16(afr1, cur.b2, acc0, 0, 0, 0);
        acc1 = __builtin_amdgcn_mfma_f32_16x16x32_bf16(afr1, cur.b3, acc1, 0, 0, 0);
        cur = nxt;
    }

    // write C (bf16); Q side pre-scaled. C layout: col=lane&15, row=quad*4+reg
    float cscale = isK ? 1.0f : SCALE_LOG2E;
    #pragma unroll
    for (int r = 0; r < 4; ++r) {
        int row = row0 + quad * 4 + r;
        outp[(size_t)row * 128 + col0 + m]      = __float2bfloat16(acc0[r] * cscale);
        outp[(size_t)row * 128 + col0 + 16 + m] = __float2bfloat16(acc1[r] * cscale);
    }
}

// ---------------------------------------------------------------------------
// Kernel C: flash-style attention row-sums. Q-fragments in registers
// (loop-invariant); K tile round-trips LDS with register prefetch.
// grid 512 = 64 q-blocks x 8 t-chunks. p = exp2(S) since Q pre-scaled.
// ---------------------------------------------------------------------------
__global__ __launch_bounds__(256, 2) void k_attn(
        const __hip_bfloat16* __restrict__ Qb, const __hip_bfloat16* __restrict__ Kb,
        const float* __restrict__ vs_g,
        float* __restrict__ num_g, float* __restrict__ den_g) {
    constexpr int LDK = 136;  // 128 + 8 pad
    __shared__ alignas(16) __hip_bfloat16 sK[128 * LDK];
    __shared__ float sVS[1024];

    int bid = blockIdx.x;
    int qb = bid >> 3, tc = bid & 7;
    int q0 = qb * 128, t0 = tc * 1024;

    int t = threadIdx.x;
    int wave = t >> 6, lane = t & 63;
    int wr = wave >> 1, wc = wave & 1;
    int m = lane & 15, quad = lane >> 4;

    bf16x8 qf[4][4];
    #pragma unroll
    for (int i = 0; i < 4; ++i)
        #pragma unroll
        for (int kk = 0; kk < 4; ++kk)
            qf[kk][i] = load_bf8(Qb + (size_t)(q0 + wr * 64 + i * 16 + m) * 128 + kk * 32 + quad * 8);

    #pragma unroll
    for (int p = 0; p < 4; ++p) sVS[p * 256 + t] = vs_g[t0 + p * 256 + t];

    u32x4v kreg[8];
    #pragma unroll
    for (int p = 0; p < 8; ++p) {
        int f = p * 256 + t;
        int r = f >> 4, c = (f & 15) * 8;
        kreg[p] = *(const u32x4v*)(Kb + (size_t)(t0 + r) * 128 + c);
    }

    float num_acc[4][4], den_acc[4][4];
    #pragma unroll
    for (int i = 0; i < 4; ++i)
        #pragma unroll
        for (int r = 0; r < 4; ++r) { num_acc[i][r] = 0.f; den_acc[i][r] = 0.f; }

    for (int it = 0; it < 8; ++it) {
        __syncthreads();
        #pragma unroll
        for (int p = 0; p < 8; ++p) {
            int f = p * 256 + t;
            int r = f >> 4, c = (f & 15) * 8;
            *(u32x4v*)(&sK[r * LDK + c]) = kreg[p];
        }
        __syncthreads();
        if (it < 7) {
            #pragma unroll
            for (int p = 0; p < 8; ++p) {
                int f = p * 256 + t;
                int r = f >> 4, c = (f & 15) * 8;
                kreg[p] = *(const u32x4v*)(Kb + (size_t)(t0 + (it + 1) * 128 + r) * 128 + c);
            }
        }

        floatx4 acc[4][4];
        #pragma unroll
        for (int i = 0; i < 4; ++i)
            #pragma unroll
            for (int j = 0; j < 4; ++j) acc[i][j] = {0.f, 0.f, 0.f, 0.f};

        #pragma unroll
        for (int kk = 0; kk < 4; ++kk) {
            bf16x8 bfr[4];
            #pragma unroll
            for (int j = 0; j < 4; ++j)
                bfr[j] = load_bf8(&sK[(wc * 64 + j * 16 + m) * LDK + kk * 32 + quad * 8]);
            #pragma unroll
            for (int i = 0; i < 4; ++i)
                #pragma unroll
                for (int j = 0; j < 4; ++j)
                    acc[i][j] = __builtin_amdgcn_mfma_f32_16x16x32_bf16(qf[kk][i], bfr[j], acc[i][j], 0, 0, 0);
        }

        #pragma unroll
        for (int j = 0; j < 4; ++j) {
            float vsv = sVS[it * 128 + wc * 64 + j * 16 + m];
            #pragma unroll
            for (int i = 0; i < 4; ++i)
                #pragma unroll
                for (int r = 0; r < 4; ++r) {
                    float p = __builtin_amdgcn_exp2f(acc[i][j][r]);
                    den_acc[i][r] += p;
                    num_acc[i][r] += p * vsv;
                }
        }
    }

    #pragma unroll
    for (int i = 0; i < 4; ++i)
        #pragma unroll
        for (int r = 0; r < 4; ++r) {
            float n = num_acc[i][r], d = den_acc[i][r];
            #pragma unroll
            for (int mask = 1; mask <= 8; mask <<= 1) {
                n += __shfl_xor(n, mask, 64);
                d += __shfl_xor(d, mask, 64);
            }
            if ((lane & 15) == 0) {
                int row = q0 + wr * 64 + i * 16 + quad * 4 + r;
                atomicAdd(&num_g[row], n);
                atomicAdd(&den_g[row], d);
            }
        }
}

// ---------------------------------------------------------------------------
// Kernel D: gated = x1 * (1 - num/den). float4 grid-mapped, memory-bound.
// ---------------------------------------------------------------------------
__global__ void k_final(const float* __restrict__ x1,
                        const float* __restrict__ num_g,
                        const float* __restrict__ den_g,
                        float* __restrict__ outp) {
    int idx = blockIdx.x * 256 + threadIdx.x;  // float4 index, 192 per row
    int s = idx / 192;
    float4 v = *(const float4*)(x1 + (size_t)idx * 4);
    float g = 1.0f - num_g[s] / den_g[s];
    float4 rv;
    rv.x = v.x * g; rv.y = v.y * g; rv.z = v.z * g; rv.w = v.w * g;
    *(float4*)(outp + (size_t)idx * 4) = rv;
}

// ---------------------------------------------------------------------------
extern "C" void kernel_launch(void* const* d_in, const int* in_sizes, int n_in,
                              void* d_out, int out_size, void* d_ws, size_t ws_size,
                              hipStream_t stream) {
    const float* x1  = (const float*)d_in[0];
    const float* x2  = (const float*)d_in[1];
    const float* w_q = (const float*)d_in[2];
    const float* w_k = (const float*)d_in[3];
    const float* w_v = (const float*)d_in[4];
    const float* w_o = (const float*)d_in[5];
    float* outp = (float*)d_out;

    char* ws = (char*)d_ws;
    __hip_bfloat16* wq_bf = (__hip_bfloat16*)(ws + 0);        // 196608 B
    __hip_bfloat16* wk_bf = (__hip_bfloat16*)(ws + 196608);   // 196608 B
    float* c_buf          = (float*)(ws + 393216);            // 3072 B
    __hip_bfloat16* Qb    = (__hip_bfloat16*)(ws + 396288);   // 2 MB
    __hip_bfloat16* Kb    = (__hip_bfloat16*)(ws + 2493440);  // 2 MB
    float* vs_g           = (float*)(ws + 4590592);           // 32 KB
    float* num_g          = (float*)(ws + 4623360);           // 32 KB
    float* den_g          = (float*)(ws + 4656128);           // 32 KB (contig after num_g)

    k_prep<<<132, 256, 0, stream>>>(w_q, w_k, w_v, w_o, wq_bf, wk_bf, c_buf, num_g);
    k_qk<<<1280, 256, 0, stream>>>(x1, x2, wq_bf, wk_bf, c_buf, Qb, Kb, vs_g);
    k_attn<<<512, 256, 0, stream>>>(Qb, Kb, vs_g, num_g, den_g);
    k_final<<<6144, 256, 0, stream>>>(x1, num_g, den_g, outp);
}

// Round 5
// 152.570 us; speedup vs baseline: 1.1892x; 1.1672x over previous
//
#include <hip/hip_runtime.h>
#include <hip/hip_bf16.h>
#include <stdint.h>

// exp(s/sqrt(128)) = exp2(s * log2(e)/sqrt(128)); folded into Q at k_qk epilogue
#define SCALE_LOG2E 0.12751743f

typedef __bf16 bf16x8 __attribute__((ext_vector_type(8)));
typedef float floatx4 __attribute__((ext_vector_type(4)));
typedef uint32_t u32x4v __attribute__((ext_vector_type(4)));

__device__ __forceinline__ bf16x8 load_bf8(const void* p) {
    u32x4v v = *(const u32x4v*)p;
    return __builtin_bit_cast(bf16x8, v);
}

__device__ __forceinline__ bf16x8 cvt8(float4 u, float4 v) {
    union { bf16x8 v8; __hip_bfloat16 h[8]; } r;
    r.h[0] = __float2bfloat16(u.x); r.h[1] = __float2bfloat16(u.y);
    r.h[2] = __float2bfloat16(u.z); r.h[3] = __float2bfloat16(u.w);
    r.h[4] = __float2bfloat16(v.x); r.h[5] = __float2bfloat16(v.y);
    r.h[6] = __float2bfloat16(v.z); r.h[7] = __float2bfloat16(v.w);
    return r.v8;
}

// async 16B global -> LDS DMA (no VGPR destination; compiler cannot collapse)
__device__ __forceinline__ void dma16(const void* g, void* l) {
    __builtin_amdgcn_global_load_lds(
        (const __attribute__((address_space(1))) uint32_t*)g,
        (__attribute__((address_space(3))) uint32_t*)l, 16, 0, 0);
}

// ---------------------------------------------------------------------------
// Kernel A: cvt w_q,w_k -> bf16 (b<96); c[768] = w_o @ w_v (b 96..98);
// zero num/den (b 99..131; num_g/den_g contiguous 16384 floats in ws).
// ---------------------------------------------------------------------------
__global__ void k_prep(const float* __restrict__ w_q, const float* __restrict__ w_k,
                       const float* __restrict__ w_v, const float* __restrict__ w_o,
                       __hip_bfloat16* __restrict__ wq_bf,
                       __hip_bfloat16* __restrict__ wk_bf,
                       float* __restrict__ c_out,
                       float* __restrict__ numden) {
    int b = blockIdx.x;
    int t = threadIdx.x;
    if (b < 96) {
        #pragma unroll
        for (int p = 0; p < 8; ++p) {
            int i = b * 2048 + p * 256 + t;
            if (i < 98304) wq_bf[i] = __float2bfloat16(w_q[i]);
            else           wk_bf[i - 98304] = __float2bfloat16(w_k[i - 98304]);
        }
    } else if (b < 99) {
        int j = (b - 96) * 256 + t;
        float acc = 0.f;
        #pragma unroll 8
        for (int k = 0; k < 64; ++k) acc += w_o[k] * w_v[k * 768 + j];
        c_out[j] = acc;
    } else {
        int z = (b - 99) * 512 + t * 2;
        if (z < 16384) { numden[z] = 0.f; numden[z + 1] = 0.f; }
    }
}

// ---------------------------------------------------------------------------
// Kernel B: Q = x1 @ w_q^T * SCALE (bid 0..255), K = x2 @ w_k^T (256..511),
// vs = x2 . c (bid 512..767).
// m97-style: block = 32 rows x 128 cols, BK=128, 6 K-iters. A-tile (32x128 f32,
// 16 KB) double-buffered in LDS via global_load_lds width=16 (async DMA, no
// VGPR pressure -> all tile loads in flight at once). B-frags direct from
// L2-resident bf16 weights. A chunks XOR-swizzled (c^(r&7)) at the global-
// source side so ds_read_b128 fragment reads are bank-conflict-free, since
// DMA forbids LDS row padding.
// ---------------------------------------------------------------------------
__global__ __launch_bounds__(256, 4) void k_qk(
        const float* __restrict__ x1, const float* __restrict__ x2,
        const __hip_bfloat16* __restrict__ wq_bf,
        const __hip_bfloat16* __restrict__ wk_bf,
        const float* __restrict__ c_in,
        __hip_bfloat16* __restrict__ Qb, __hip_bfloat16* __restrict__ Kb,
        float* __restrict__ vs_g) {
    __shared__ alignas(16) float sA[2][32 * 128];  // 2 x 16 KB, swizzled 16B chunks

    int bid = blockIdx.x;
    int t = threadIdx.x;

    if (bid >= 512) {
        // ---- vs blocks: 256 blocks x 32 rows, 8 threads per row ----
        int vb = bid - 512;
        int r = vb * 32 + (t >> 3), h = t & 7;
        const float* xr = x2 + (size_t)r * 768 + h * 96;
        const float* cr = c_in + h * 96;
        float vacc = 0.f;
        #pragma unroll 6
        for (int j = 0; j < 96; j += 4) {
            float4 v = *(const float4*)(xr + j);
            vacc += v.x * cr[j] + v.y * cr[j + 1] + v.z * cr[j + 2] + v.w * cr[j + 3];
        }
        vacc += __shfl_xor(vacc, 1, 64);
        vacc += __shfl_xor(vacc, 2, 64);
        vacc += __shfl_xor(vacc, 4, 64);
        if (h == 0) vs_g[r] = vacc;
        return;
    }

    bool isK = bid >= 256;
    int row0 = (bid & 255) * 32;
    const float* x = isK ? x2 : x1;
    const __hip_bfloat16* w = isK ? wk_bf : wq_bf;
    __hip_bfloat16* outp = isK ? Kb : Qb;

    int wave = t >> 6, lane = t & 63;
    int m = lane & 15, quad = lane >> 4;
    int col0 = wave * 32;

    // Per-thread DMA source mapping (constant across iters, only kc changes).
    // Tile = 32 rows x 32 chunks (16B). Slot s = wave*256 + p*64 + lane.
    // r = s>>5, pos = s&31; global chunk stored at pos is c = pos ^ (r&7).
    const float* gsrc[4];
    #pragma unroll
    for (int p = 0; p < 4; ++p) {
        int s = wave * 256 + p * 64 + lane;
        int r = s >> 5, pos = s & 31;
        int c = pos ^ (r & 7);
        gsrc[p] = x + (size_t)(row0 + r) * 768 + c * 4;
    }
    // wave-uniform LDS bases for the 4 DMA instructions (HW adds lane*16)
    auto dma_tile = [&](int buf, int kc) {
        #pragma unroll
        for (int p = 0; p < 4; ++p)
            dma16(gsrc[p] + kc, &sA[buf][(wave * 256 + p * 64) * 4]);
    };

    const __hip_bfloat16* bp = w + (size_t)(col0 + m) * 768 + quad * 8;

    floatx4 acc[2][2];
    #pragma unroll
    for (int i = 0; i < 2; ++i)
        #pragma unroll
        for (int j = 0; j < 2; ++j) acc[i][j] = {0.f, 0.f, 0.f, 0.f};

    dma_tile(0, 0);

    for (int it = 0; it < 6; ++it) {
        __syncthreads();            // drains all DMAs (incl. tile it); frees buf (it+1)&1
        if (it < 5) dma_tile((it + 1) & 1, (it + 1) * 128);

        const float* A = sA[it & 1];
        int kc = it * 128;
        #pragma unroll
        for (int ks = 0; ks < 4; ++ks) {
            bf16x8 afr[2], bfr[2];
            #pragma unroll
            for (int i = 0; i < 2; ++i) {
                int r = i * 16 + m;
                int cb = ks * 8 + quad * 2;
                int p0 = cb ^ (r & 7), p1 = (cb + 1) ^ (r & 7);
                float4 f0 = *(const float4*)&A[r * 128 + p0 * 4];
                float4 f1 = *(const float4*)&A[r * 128 + p1 * 4];
                afr[i] = cvt8(f0, f1);
            }
            #pragma unroll
            for (int j = 0; j < 2; ++j)
                bfr[j] = load_bf8(bp + (size_t)j * 16 * 768 + kc + ks * 32);
            #pragma unroll
            for (int i = 0; i < 2; ++i)
                #pragma unroll
                for (int j = 0; j < 2; ++j)
                    acc[i][j] = __builtin_amdgcn_mfma_f32_16x16x32_bf16(afr[i], bfr[j], acc[i][j], 0, 0, 0);
        }
    }

    // write C (bf16); Q side pre-scaled. C layout: col=lane&15, row=quad*4+reg
    float cscale = isK ? 1.0f : SCALE_LOG2E;
    #pragma unroll
    for (int i = 0; i < 2; ++i)
        #pragma unroll
        for (int j = 0; j < 2; ++j)
            #pragma unroll
            for (int r = 0; r < 4; ++r) {
                int row = row0 + i * 16 + quad * 4 + r;
                int col = col0 + j * 16 + m;
                outp[(size_t)row * 128 + col] = __float2bfloat16(acc[i][j][r] * cscale);
            }
}

// ---------------------------------------------------------------------------
// Kernel C: flash-style attention row-sums. Q-fragments in registers
// (loop-invariant); K tile round-trips LDS with register prefetch.
// grid 512 = 64 q-blocks x 8 t-chunks. p = exp2(S) since Q pre-scaled.
// ---------------------------------------------------------------------------
__global__ __launch_bounds__(256, 2) void k_attn(
        const __hip_bfloat16* __restrict__ Qb, const __hip_bfloat16* __restrict__ Kb,
        const float* __restrict__ vs_g,
        float* __restrict__ num_g, float* __restrict__ den_g) {
    constexpr int LDK = 136;  // 128 + 8 pad
    __shared__ alignas(16) __hip_bfloat16 sK[128 * LDK];
    __shared__ float sVS[1024];

    int bid = blockIdx.x;
    int qb = bid >> 3, tc = bid & 7;
    int q0 = qb * 128, t0 = tc * 1024;

    int t = threadIdx.x;
    int wave = t >> 6, lane = t & 63;
    int wr = wave >> 1, wc = wave & 1;
    int m = lane & 15, quad = lane >> 4;

    bf16x8 qf[4][4];
    #pragma unroll
    for (int i = 0; i < 4; ++i)
        #pragma unroll
        for (int kk = 0; kk < 4; ++kk)
            qf[kk][i] = load_bf8(Qb + (size_t)(q0 + wr * 64 + i * 16 + m) * 128 + kk * 32 + quad * 8);

    #pragma unroll
    for (int p = 0; p < 4; ++p) sVS[p * 256 + t] = vs_g[t0 + p * 256 + t];

    u32x4v kreg[8];
    #pragma unroll
    for (int p = 0; p < 8; ++p) {
        int f = p * 256 + t;
        int r = f >> 4, c = (f & 15) * 8;
        kreg[p] = *(const u32x4v*)(Kb + (size_t)(t0 + r) * 128 + c);
    }

    float num_acc[4][4], den_acc[4][4];
    #pragma unroll
    for (int i = 0; i < 4; ++i)
        #pragma unroll
        for (int r = 0; r < 4; ++r) { num_acc[i][r] = 0.f; den_acc[i][r] = 0.f; }

    for (int it = 0; it < 8; ++it) {
        __syncthreads();
        #pragma unroll
        for (int p = 0; p < 8; ++p) {
            int f = p * 256 + t;
            int r = f >> 4, c = (f & 15) * 8;
            *(u32x4v*)(&sK[r * LDK + c]) = kreg[p];
        }
        __syncthreads();
        if (it < 7) {
            #pragma unroll
            for (int p = 0; p < 8; ++p) {
                int f = p * 256 + t;
                int r = f >> 4, c = (f & 15) * 8;
                kreg[p] = *(const u32x4v*)(Kb + (size_t)(t0 + (it + 1) * 128 + r) * 128 + c);
            }
        }

        floatx4 acc[4][4];
        #pragma unroll
        for (int i = 0; i < 4; ++i)
            #pragma unroll
            for (int j = 0; j < 4; ++j) acc[i][j] = {0.f, 0.f, 0.f, 0.f};

        #pragma unroll
        for (int kk = 0; kk < 4; ++kk) {
            bf16x8 bfr[4];
            #pragma unroll
            for (int j = 0; j < 4; ++j)
                bfr[j] = load_bf8(&sK[(wc * 64 + j * 16 + m) * LDK + kk * 32 + quad * 8]);
            #pragma unroll
            for (int i = 0; i < 4; ++i)
                #pragma unroll
                for (int j = 0; j < 4; ++j)
                    acc[i][j] = __builtin_amdgcn_mfma_f32_16x16x32_bf16(qf[kk][i], bfr[j], acc[i][j], 0, 0, 0);
        }

        #pragma unroll
        for (int j = 0; j < 4; ++j) {
            float vsv = sVS[it * 128 + wc * 64 + j * 16 + m];
            #pragma unroll
            for (int i = 0; i < 4; ++i)
                #pragma unroll
                for (int r = 0; r < 4; ++r) {
                    float p = __builtin_amdgcn_exp2f(acc[i][j][r]);
                    den_acc[i][r] += p;
                    num_acc[i][r] += p * vsv;
                }
        }
    }

    #pragma unroll
    for (int i = 0; i < 4; ++i)
        #pragma unroll
        for (int r = 0; r < 4; ++r) {
            float n = num_acc[i][r], d = den_acc[i][r];
            #pragma unroll
            for (int mask = 1; mask <= 8; mask <<= 1) {
                n += __shfl_xor(n, mask, 64);
                d += __shfl_xor(d, mask, 64);
            }
            if ((lane & 15) == 0) {
                int row = q0 + wr * 64 + i * 16 + quad * 4 + r;
                atomicAdd(&num_g[row], n);
                atomicAdd(&den_g[row], d);
            }
        }
}

// ---------------------------------------------------------------------------
// Kernel D: gated = x1 * (1 - num/den). float4 grid-mapped, memory-bound.
// ---------------------------------------------------------------------------
__global__ void k_final(const float* __restrict__ x1,
                        const float* __restrict__ num_g,
                        const float* __restrict__ den_g,
                        float* __restrict__ outp) {
    int idx = blockIdx.x * 256 + threadIdx.x;  // float4 index, 192 per row
    int s = idx / 192;
    float4 v = *(const float4*)(x1 + (size_t)idx * 4);
    float g = 1.0f - num_g[s] / den_g[s];
    float4 rv;
    rv.x = v.x * g; rv.y = v.y * g; rv.z = v.z * g; rv.w = v.w * g;
    *(float4*)(outp + (size_t)idx * 4) = rv;
}

// ---------------------------------------------------------------------------
extern "C" void kernel_launch(void* const* d_in, const int* in_sizes, int n_in,
                              void* d_out, int out_size, void* d_ws, size_t ws_size,
                              hipStream_t stream) {
    const float* x1  = (const float*)d_in[0];
    const float* x2  = (const float*)d_in[1];
    const float* w_q = (const float*)d_in[2];
    const float* w_k = (const float*)d_in[3];
    const float* w_v = (const float*)d_in[4];
    const float* w_o = (const float*)d_in[5];
    float* outp = (float*)d_out;

    char* ws = (char*)d_ws;
    __hip_bfloat16* wq_bf = (__hip_bfloat16*)(ws + 0);        // 196608 B
    __hip_bfloat16* wk_bf = (__hip_bfloat16*)(ws + 196608);   // 196608 B
    float* c_buf          = (float*)(ws + 393216);            // 3072 B
    __hip_bfloat16* Qb    = (__hip_bfloat16*)(ws + 396288);   // 2 MB
    __hip_bfloat16* Kb    = (__hip_bfloat16*)(ws + 2493440);  // 2 MB
    float* vs_g           = (float*)(ws + 4590592);           // 32 KB
    float* num_g          = (float*)(ws + 4623360);           // 32 KB
    float* den_g          = (float*)(ws + 4656128);           // 32 KB (contig after num_g)

    k_prep<<<132, 256, 0, stream>>>(w_q, w_k, w_v, w_o, wq_bf, wk_bf, c_buf, num_g);
    k_qk<<<768, 256, 0, stream>>>(x1, x2, wq_bf, wk_bf, c_buf, Qb, Kb, vs_g);
    k_attn<<<512, 256, 0, stream>>>(Qb, Kb, vs_g, num_g, den_g);
    k_final<<<6144, 256, 0, stream>>>(x1, num_g, den_g, outp);
}